// Round 9
// baseline (157.134 us; speedup 1.0000x reference)
//
#include <hip/hip_runtime.h>

typedef unsigned short u16;
typedef unsigned int u32;
typedef __attribute__((ext_vector_type(8))) short bf16x8;
typedef __attribute__((ext_vector_type(4))) float f32x4;

__device__ __forceinline__ u16 f2bf(float x) {
  unsigned u = __float_as_uint(x);
  u += 0x7fffu + ((u >> 16) & 1u);   // RNE
  return (u16)(u >> 16);
}
__device__ __forceinline__ float bf2f(u16 z) {
  return __uint_as_float((u32)z << 16);
}
__device__ __forceinline__ u32 cvtpk(float lo, float hi) {
  u32 r;
  asm("v_cvt_pk_bf16_f32 %0, %1, %2" : "=v"(r) : "v"(lo), "v"(hi));
  return r;
}

// ---- merged prep: blocks 0..2047 cast x fp32->bf16 (+rope table);
// ----              blocks 2048..3071 transpose+cast the 4 weights ----
__global__ __launch_bounds__(256) void prep(const float* __restrict__ x,
                                            const float* __restrict__ W0,
                                            const float* __restrict__ W1,
                                            const float* __restrict__ W2,
                                            const float* __restrict__ W3,
                                            u16* __restrict__ xb,
                                            u16* __restrict__ Wt,
                                            float2* __restrict__ rtab) {
  __shared__ alignas(16) u16 ls[64 * 72];
  int b = blockIdx.x;
  int tid = threadIdx.x;
  if (b < 2048) {
    int g = b * 256 + tid;
    int i = g * 4;
    float4 f = *(const float4*)(x + i);
    ushort4 o;
    o.x = f2bf(f.x); o.y = f2bf(f.y); o.z = f2bf(f.z); o.w = f2bf(f.w);
    *(ushort4*)(xb + i) = o;
    if (g < 2048 * 16) {
      int t = g >> 4, ii = g & 15;
      float fr = exp2f(-10.0f * (float)ii / 15.0f);
      float th = (float)t * fr;
      rtab[g] = make_float2(cosf(th), sinf(th));
    }
    return;
  }
  int bb = b - 2048;
  int z = bb >> 8;
  int rem = bb & 255;
  const float* W = (z == 0) ? W0 : (z == 1) ? W1 : (z == 2) ? W2 : W3;
  u16* o = Wt + (size_t)z * (1024u * 1024u);
  int kt = (rem >> 4) * 64, nt = (rem & 15) * 64;
  int r = tid >> 2, c0 = (tid & 3) * 16;
  const float* src = W + (size_t)(kt + r) * 1024 + nt + c0;
  u16 tmp[16];
#pragma unroll
  for (int c = 0; c < 16; c += 4) {
    float4 f = *(const float4*)(src + c);
    tmp[c + 0] = f2bf(f.x); tmp[c + 1] = f2bf(f.y);
    tmp[c + 2] = f2bf(f.z); tmp[c + 3] = f2bf(f.w);
  }
#pragma unroll
  for (int c = 0; c < 16; ++c) ls[r * 72 + c0 + c] = tmp[c];
  __syncthreads();
#pragma unroll
  for (int pass = 0; pass < 4; ++pass) {
    int n = pass * 16 + (tid >> 4);
    int kk = (tid & 15) * 4;
    ushort4 val;
    val.x = ls[(kk + 0) * 72 + n];
    val.y = ls[(kk + 1) * 72 + n];
    val.z = ls[(kk + 2) * 72 + n];
    val.w = ls[(kk + 3) * 72 + n];
    *(ushort4*)(o + (size_t)(nt + n) * 1024 + kt + kk) = val;
  }
}

#define GLD 40  // LDS stride: rows alias at +8 -> 2-way on banks (free)

// ---- fused QKV GEMM 128x128, full K=1024, reg-staged + prefetch (r7 form) ----
__global__ __launch_bounds__(256) void gemm_qkv(const u16* __restrict__ A,
                                                const u16* __restrict__ Wt,
                                                u16* __restrict__ qb,
                                                u16* __restrict__ kb,
                                                u16* __restrict__ vt,
                                                const float* __restrict__ s_qk,
                                                const float2* __restrict__ rtab) {
  __shared__ alignas(16) u16 As[128 * GLD];
  __shared__ alignas(16) u16 Bs[128 * GLD];
  int z = blockIdx.z;
  const u16* B = Wt + (size_t)z * (1024u * 1024u);
  int tid = threadIdx.x;
  int bm = blockIdx.y * 128, bn = blockIdx.x * 128;
  int lane = tid & 63, w = tid >> 6;
  int wm = (w >> 1) * 64, wn = (w & 1) * 64;
  int m16 = lane & 15, q = lane >> 4;
  f32x4 acc[4][4] = {};
  int srow = tid >> 1, scol = (tid & 1) * 16;
  const u16* aptr = A + (size_t)(bm + srow) * 1024 + scol;
  const u16* bptr = B + (size_t)(bn + srow) * 1024 + scol;
  uint4 a0 = *(const uint4*)(aptr);
  uint4 a1 = *(const uint4*)(aptr + 8);
  uint4 b0 = *(const uint4*)(bptr);
  uint4 b1 = *(const uint4*)(bptr + 8);
  for (int k0 = 0; k0 < 1024; k0 += 32) {
    __syncthreads();
    *(uint4*)&As[srow * GLD + scol] = a0;
    *(uint4*)&As[srow * GLD + scol + 8] = a1;
    *(uint4*)&Bs[srow * GLD + scol] = b0;
    *(uint4*)&Bs[srow * GLD + scol + 8] = b1;
    uint4 na0, na1, nb0, nb1;
    if (k0 < 992) {
      na0 = *(const uint4*)(aptr + k0 + 32);
      na1 = *(const uint4*)(aptr + k0 + 40);
      nb0 = *(const uint4*)(bptr + k0 + 32);
      nb1 = *(const uint4*)(bptr + k0 + 40);
    }
    __syncthreads();
    bf16x8 af[4], bfr[4];
#pragma unroll
    for (int mt = 0; mt < 4; ++mt)
      af[mt] = *(const bf16x8*)&As[(wm + mt * 16 + m16) * GLD + q * 8];
#pragma unroll
    for (int nt = 0; nt < 4; ++nt)
      bfr[nt] = *(const bf16x8*)&Bs[(wn + nt * 16 + m16) * GLD + q * 8];
#pragma unroll
    for (int mt = 0; mt < 4; ++mt)
#pragma unroll
      for (int nt = 0; nt < 4; ++nt)
        acc[mt][nt] = __builtin_amdgcn_mfma_f32_16x16x32_bf16(af[mt], bfr[nt], acc[mt][nt], 0, 0, 0);
    if (k0 < 992) { a0 = na0; a1 = na1; b0 = nb0; b1 = nb1; }
  }
  int hh = (bn + wn) >> 6;
  if (z == 2) {
#pragma unroll
    for (int nt = 0; nt < 4; ++nt) {
      int n = bn + wn + nt * 16 + m16;
#pragma unroll
      for (int mt = 0; mt < 4; ++mt) {
        int t0 = bm + wm + mt * 16 + q * 4;
        ushort4 val;
        val.x = f2bf(acc[mt][nt][0]);
        val.y = f2bf(acc[mt][nt][1]);
        val.z = f2bf(acc[mt][nt][2]);
        val.w = f2bf(acc[mt][nt][3]);
        *(ushort4*)(vt + (size_t)n * 2048 + t0) = val;
      }
    }
  } else {
    u16* dst = z ? kb : qb;
    float se0 = s_qk[hh * 64 +  0 + m16] * 32.0f;   // sqrt(1024)=32
    float se1 = s_qk[hh * 64 + 16 + m16] * 32.0f;
    float se2 = s_qk[hh * 64 + 32 + m16] * 32.0f;
    float se3 = s_qk[hh * 64 + 48 + m16] * 32.0f;
#pragma unroll
    for (int mt = 0; mt < 4; ++mt)
#pragma unroll
      for (int r = 0; r < 4; ++r) {
        float ss = acc[mt][0][r] * acc[mt][0][r] + acc[mt][1][r] * acc[mt][1][r]
                 + acc[mt][2][r] * acc[mt][2][r] + acc[mt][3][r] * acc[mt][3][r];
        ss += __shfl_xor(ss, 1); ss += __shfl_xor(ss, 2);
        ss += __shfl_xor(ss, 4); ss += __shfl_xor(ss, 8);
        float inv = rsqrtf(ss + 1e-12f);
        int t = bm + wm + mt * 16 + q * 4 + r;
        float2 cs = rtab[t * 16 + m16];
        float x0 = acc[mt][0][r] * inv * se0;
        float x1 = acc[mt][1][r] * inv * se1;
        float x2 = acc[mt][2][r] * inv * se2;
        float x3 = acc[mt][3][r] * inv * se3;
        size_t off = (size_t)t * 1024 + hh * 64 + m16;
        dst[off]      = f2bf(x0 * cs.x + x2 * cs.y);
        dst[off + 16] = f2bf(x1);
        dst[off + 32] = f2bf(x2 * cs.x - x0 * cs.y);
        dst[off + 48] = f2bf(x3);
      }
  }
}

// ------- MFMA flash attention, 32-row q-tiles, key-split waves, 4 waves/SIMD -------
// grid (16 h, 64 y); 256 thr = 4 waves; qt = 63-y (heavy first). 1024 blocks,
// LDS 37.4KB -> 4 blocks/CU co-resident -> 4 waves/SIMD TLP (vs r7's 2).
// Wave w owns keys [kb0+w*32,+32) of each 128-key block, partial Y[32 q][64 d].
// Q frags hoisted; K/V frags wave-disjoint, direct from global (L2-resident).
// No barriers in loop; 4-slice LDS combine at the end (2 barriers).
#define PLD 40   // P row stride (u16): 32 keys + 8 pad
#define YSR 36   // combine slice row stride (f32): 32 rows + 4 pad
__global__ __launch_bounds__(256) void attn_flash(const u16* __restrict__ qb,
                                                  const u16* __restrict__ kb,
                                                  const u16* __restrict__ vt,
                                                  u16* __restrict__ yb) {
  // Ys: 4 slices [64 col][YSR] f32 = 36864 B; Lb: [4][32] f32 = 512 B.
  // P buffers (4 x [32 q][PLD] u16 = 10240 B) alias Ys front; barrier-separated.
  __shared__ alignas(16) unsigned char smb[4 * 64 * YSR * 4 + 4 * 32 * 4];
  int h = blockIdx.x;
  int qt = 63 - blockIdx.y;            // heavy q-tiles dispatch first
  int t0 = qt * 32;
  int tid = threadIdx.x;
  int lane = tid & 63, w = tid >> 6;
  int m16 = lane & 15, q = lane >> 4;
  u16* pw = (u16*)smb + w * 32 * PLD;
  bf16x8 qa[2][2];
#pragma unroll
  for (int qn = 0; qn < 2; ++qn) {
    const u16* qr = qb + (size_t)(t0 + qn * 16 + m16) * 1024 + h * 64;
    qa[qn][0] = *(const bf16x8*)(qr + q * 8);
    qa[qn][1] = *(const bf16x8*)(qr + 32 + q * 8);
  }
  int wk = w * 32;   // wave's key offset within a 128-key block
  const u16* kbase = kb + (size_t)(wk + m16) * 1024 + h * 64 + q * 8;
  const u16* vbase = vt + (size_t)(h * 64 + m16) * 2048 + wk + q * 8;
  f32x4 Yacc[2][4] = {};
  float lsum[2] = {0.f, 0.f};
  int nkb = (qt + 4) >> 2;             // 128-key blocks covering keys <= t0+31
  for (int kbi = 0; kbi < nkb; ++kbi) {
    int kb0 = kbi * 128;
    bf16x8 kfr[2][2];
#pragma unroll
    for (int kt = 0; kt < 2; ++kt) {
      const u16* kp = kbase + (size_t)kb0 * 1024 + kt * 16384;
      kfr[kt][0] = *(const bf16x8*)kp;
      kfr[kt][1] = *(const bf16x8*)(kp + 32);
    }
    bf16x8 vfr[4];
#pragma unroll
    for (int nt = 0; nt < 4; ++nt)
      vfr[nt] = *(const bf16x8*)(vbase + (size_t)nt * 32768 + kb0);
    // ---- S^T[key][q] = mfma(K, Q)
    f32x4 ST[2][2] = {};
#pragma unroll
    for (int kt = 0; kt < 2; ++kt)
#pragma unroll
      for (int qn = 0; qn < 2; ++qn) {
        ST[kt][qn] = __builtin_amdgcn_mfma_f32_16x16x32_bf16(kfr[kt][0], qa[qn][0], ST[kt][qn], 0, 0, 0);
        ST[kt][qn] = __builtin_amdgcn_mfma_f32_16x16x32_bf16(kfr[kt][1], qa[qn][1], ST[kt][qn], 0, 0, 0);
      }
    // ---- exp + causal mask (only last block reaches the diagonal), pack, P->LDS
    bool last = (kbi == nkb - 1);
#pragma unroll
    for (int kt = 0; kt < 2; ++kt) {
      int keyb = kb0 + wk + kt * 16 + q * 4;
#pragma unroll
      for (int qn = 0; qn < 2; ++qn) {
        int qr_ = t0 + qn * 16 + m16;
        float p0 = __builtin_amdgcn_exp2f(ST[kt][qn][0] * 0.17312340490667562f);
        float p1 = __builtin_amdgcn_exp2f(ST[kt][qn][1] * 0.17312340490667562f);
        float p2 = __builtin_amdgcn_exp2f(ST[kt][qn][2] * 0.17312340490667562f);
        float p3 = __builtin_amdgcn_exp2f(ST[kt][qn][3] * 0.17312340490667562f);
        if (last) {
          p0 = (keyb + 0 <= qr_) ? p0 : 0.f;
          p1 = (keyb + 1 <= qr_) ? p1 : 0.f;
          p2 = (keyb + 2 <= qr_) ? p2 : 0.f;
          p3 = (keyb + 3 <= qr_) ? p3 : 0.f;
        }
        lsum[qn] += (p0 + p1) + (p2 + p3);
        uint2 pk2;
        pk2.x = cvtpk(p0, p1);
        pk2.y = cvtpk(p2, p3);
        *(uint2*)&pw[(qn * 16 + m16) * PLD + kt * 16 + q * 4] = pk2;
      }
    }
    // ---- PV over the wave's 32 keys
    bf16x8 pa[2];
#pragma unroll
    for (int qn = 0; qn < 2; ++qn)
      pa[qn] = *(const bf16x8*)&pw[(qn * 16 + m16) * PLD + q * 8];
#pragma unroll
    for (int qn = 0; qn < 2; ++qn)
#pragma unroll
      for (int nt = 0; nt < 4; ++nt)
        Yacc[qn][nt] = __builtin_amdgcn_mfma_f32_16x16x32_bf16(pa[qn], vfr[nt], Yacc[qn][nt], 0, 0, 0);
  }
  // ---- per-wave row sums (reduce over lane-q groups)
#pragma unroll
  for (int qn = 0; qn < 2; ++qn) {
    lsum[qn] += __shfl_xor(lsum[qn], 16);
    lsum[qn] += __shfl_xor(lsum[qn], 32);
  }
  __syncthreads();   // all P reads done; combine region aliases P
  float* Ys = (float*)smb;                         // [ws][64 col][YSR]
  float* Lb = (float*)(smb + 4 * 64 * YSR * 4);    // [ws][32]
  if (q == 0) {
    Lb[w * 32 + m16] = lsum[0];
    Lb[w * 32 + 16 + m16] = lsum[1];
  }
#pragma unroll
  for (int qn = 0; qn < 2; ++qn)
#pragma unroll
    for (int nt = 0; nt < 4; ++nt)
      *(f32x4*)&Ys[(w * 64 + nt * 16 + m16) * YSR + qn * 16 + q * 4] = Yacc[qn][nt];
  __syncthreads();
  // wave w owns output rows [w*8, w*8+8); lane handles col c, rows r0..r0+3
  int r0 = w * 8 + (q & 1) * 4;
  float Lt[4];
#pragma unroll
  for (int r = 0; r < 4; ++r)
    Lt[r] = (Lb[r0 + r] + Lb[32 + r0 + r]) + (Lb[64 + r0 + r] + Lb[96 + r0 + r]);
#pragma unroll
  for (int p = 0; p < 2; ++p) {
    int c = m16 + (q >> 1) * 16 + p * 32;
    f32x4 s = {0.f, 0.f, 0.f, 0.f};
#pragma unroll
    for (int ws = 0; ws < 4; ++ws)
      s += *(const f32x4*)&Ys[(ws * 64 + c) * YSR + r0];
#pragma unroll
    for (int r = 0; r < 4; ++r)
      yb[(size_t)(t0 + r0 + r) * 1024 + h * 64 + c] =
          f2bf(s[r] * __builtin_amdgcn_rcpf(Lt[r]));
  }
}

// ------- o-proj GEMM: out[2048][1024] fp32 = yb bf16 @ Wto^T, full K (r7 form) ------
__global__ __launch_bounds__(256) void gemm_o(const u16* __restrict__ A,
                                              const u16* __restrict__ B,
                                              float* __restrict__ C) {
  __shared__ alignas(16) u16 As[128 * GLD];
  __shared__ alignas(16) u16 Bs[64 * GLD];
  int tid = threadIdx.x;
  int bm = blockIdx.y * 128, bn = blockIdx.x * 64;
  int lane = tid & 63, w = tid >> 6;
  int wm = w * 32;
  int m16 = lane & 15, q = lane >> 4;
  f32x4 acc[2][4] = {};
  int srA = tid >> 1, scA = (tid & 1) * 16;
  int srB = tid >> 2, scB = (tid & 3) * 8;
  const u16* aptr = A + (size_t)(bm + srA) * 1024 + scA;
  const u16* bptr = B + (size_t)(bn + srB) * 1024 + scB;
  uint4 a0 = *(const uint4*)(aptr);
  uint4 a1 = *(const uint4*)(aptr + 8);
  uint4 b0 = *(const uint4*)(bptr);
  for (int k0 = 0; k0 < 1024; k0 += 32) {
    __syncthreads();
    *(uint4*)&As[srA * GLD + scA] = a0;
    *(uint4*)&As[srA * GLD + scA + 8] = a1;
    *(uint4*)&Bs[srB * GLD + scB] = b0;
    uint4 na0, na1, nb0;
    if (k0 < 992) {
      na0 = *(const uint4*)(aptr + k0 + 32);
      na1 = *(const uint4*)(aptr + k0 + 40);
      nb0 = *(const uint4*)(bptr + k0 + 32);
    }
    __syncthreads();
    bf16x8 af[2], bfr[4];
#pragma unroll
    for (int mt = 0; mt < 2; ++mt)
      af[mt] = *(const bf16x8*)&As[(wm + mt * 16 + m16) * GLD + q * 8];
#pragma unroll
    for (int nt = 0; nt < 4; ++nt)
      bfr[nt] = *(const bf16x8*)&Bs[(nt * 16 + m16) * GLD + q * 8];
#pragma unroll
    for (int mt = 0; mt < 2; ++mt)
#pragma unroll
      for (int nt = 0; nt < 4; ++nt)
        acc[mt][nt] = __builtin_amdgcn_mfma_f32_16x16x32_bf16(af[mt], bfr[nt], acc[mt][nt], 0, 0, 0);
    if (k0 < 992) { a0 = na0; a1 = na1; b0 = nb0; }
  }
#pragma unroll
  for (int mt = 0; mt < 2; ++mt)
#pragma unroll
    for (int nt = 0; nt < 4; ++nt)
#pragma unroll
      for (int r = 0; r < 4; ++r) {
        int row = bm + wm + mt * 16 + q * 4 + r;
        int col = bn + nt * 16 + m16;
        C[(size_t)row * 1024 + col] = acc[mt][nt][r];
      }
}

extern "C" void kernel_launch(void* const* d_in, const int* in_sizes, int n_in,
                              void* d_out, int out_size, void* d_ws, size_t ws_size,
                              hipStream_t stream) {
  const float* x   = (const float*)d_in[0];
  const float* Wq  = (const float*)d_in[1];
  const float* Wk  = (const float*)d_in[2];
  const float* Wv  = (const float*)d_in[3];
  const float* Wo  = (const float*)d_in[4];
  const float* sqk = (const float*)d_in[5];
  float* out = (float*)d_out;
  char* ws = (char*)d_ws;

  u16*    xb   = (u16*)ws;
  u16*    Wt   = (u16*)(ws + ((size_t)4 << 20));
  float2* rtab = (float2*)(ws + ((size_t)12 << 20));
  u16*    qb16 = (u16*)(ws + ((size_t)16 << 20));
  u16*    kb16 = (u16*)(ws + ((size_t)20 << 20));
  u16*    vt16 = (u16*)(ws + ((size_t)24 << 20));
  u16*    yb   = (u16*)(ws + ((size_t)28 << 20));
  u16*    Wto  = Wt + (size_t)3 * 1024 * 1024;

  prep<<<3072, 256, 0, stream>>>(x, Wq, Wk, Wv, Wo, xb, Wt, rtab);
  gemm_qkv<<<dim3(8, 16, 3), 256, 0, stream>>>(xb, Wt, qb16, kb16, vt16, sqk, rtab);
  attn_flash<<<dim3(16, 64), 256, 0, stream>>>(qb16, kb16, vt16, yb);
  gemm_o<<<dim3(16, 16), 256, 0, stream>>>(yb, Wto, out);
}

// Round 10
// 143.600 us; speedup vs baseline: 1.0942x; 1.0942x over previous
//
#include <hip/hip_runtime.h>

typedef unsigned short u16;
typedef unsigned int u32;
typedef __attribute__((ext_vector_type(8))) short bf16x8;
typedef __attribute__((ext_vector_type(4))) float f32x4;

__device__ __forceinline__ u16 f2bf(float x) {
  unsigned u = __float_as_uint(x);
  u += 0x7fffu + ((u >> 16) & 1u);   // RNE
  return (u16)(u >> 16);
}
__device__ __forceinline__ float bf2f(u16 z) {
  return __uint_as_float((u32)z << 16);
}
__device__ __forceinline__ u32 cvtpk(float lo, float hi) {
  u32 r;
  asm("v_cvt_pk_bf16_f32 %0, %1, %2" : "=v"(r) : "v"(lo), "v"(hi));
  return r;
}

// ---- merged prep: blocks 0..2047 cast x fp32->bf16 (+rope table);
// ----              blocks 2048..3071 transpose+cast the 4 weights ----
__global__ __launch_bounds__(256) void prep(const float* __restrict__ x,
                                            const float* __restrict__ W0,
                                            const float* __restrict__ W1,
                                            const float* __restrict__ W2,
                                            const float* __restrict__ W3,
                                            u16* __restrict__ xb,
                                            u16* __restrict__ Wt,
                                            float2* __restrict__ rtab) {
  __shared__ alignas(16) u16 ls[64 * 72];
  int b = blockIdx.x;
  int tid = threadIdx.x;
  if (b < 2048) {
    int g = b * 256 + tid;
    int i = g * 4;
    float4 f = *(const float4*)(x + i);
    ushort4 o;
    o.x = f2bf(f.x); o.y = f2bf(f.y); o.z = f2bf(f.z); o.w = f2bf(f.w);
    *(ushort4*)(xb + i) = o;
    if (g < 2048 * 16) {
      int t = g >> 4, ii = g & 15;
      float fr = exp2f(-10.0f * (float)ii / 15.0f);
      float th = (float)t * fr;
      rtab[g] = make_float2(cosf(th), sinf(th));
    }
    return;
  }
  int bb = b - 2048;
  int z = bb >> 8;
  int rem = bb & 255;
  const float* W = (z == 0) ? W0 : (z == 1) ? W1 : (z == 2) ? W2 : W3;
  u16* o = Wt + (size_t)z * (1024u * 1024u);
  int kt = (rem >> 4) * 64, nt = (rem & 15) * 64;
  int r = tid >> 2, c0 = (tid & 3) * 16;
  const float* src = W + (size_t)(kt + r) * 1024 + nt + c0;
  u16 tmp[16];
#pragma unroll
  for (int c = 0; c < 16; c += 4) {
    float4 f = *(const float4*)(src + c);
    tmp[c + 0] = f2bf(f.x); tmp[c + 1] = f2bf(f.y);
    tmp[c + 2] = f2bf(f.z); tmp[c + 3] = f2bf(f.w);
  }
#pragma unroll
  for (int c = 0; c < 16; ++c) ls[r * 72 + c0 + c] = tmp[c];
  __syncthreads();
#pragma unroll
  for (int pass = 0; pass < 4; ++pass) {
    int n = pass * 16 + (tid >> 4);
    int kk = (tid & 15) * 4;
    ushort4 val;
    val.x = ls[(kk + 0) * 72 + n];
    val.y = ls[(kk + 1) * 72 + n];
    val.z = ls[(kk + 2) * 72 + n];
    val.w = ls[(kk + 3) * 72 + n];
    *(ushort4*)(o + (size_t)(nt + n) * 1024 + kt + kk) = val;
  }
}

#define GLD2 72  // LDS stride for BK=64 tiles: rows alias at +8 -> 2-way (free)

// ---- fused QKV GEMM 128x128, full K=1024, BK=64 (16 iters, half the barriers) ----
// reg-staged + prefetch (r8 showed gload_lds loses here); epilogue unchanged.
__global__ __launch_bounds__(256) void gemm_qkv(const u16* __restrict__ A,
                                                const u16* __restrict__ Wt,
                                                u16* __restrict__ qb,
                                                u16* __restrict__ kb,
                                                u16* __restrict__ vt,
                                                const float* __restrict__ s_qk,
                                                const float2* __restrict__ rtab) {
  __shared__ alignas(16) u16 As[128 * GLD2];
  __shared__ alignas(16) u16 Bs[128 * GLD2];
  int z = blockIdx.z;
  const u16* B = Wt + (size_t)z * (1024u * 1024u);
  int tid = threadIdx.x;
  int bm = blockIdx.y * 128, bn = blockIdx.x * 128;
  int lane = tid & 63, w = tid >> 6;
  int wm = (w >> 1) * 64, wn = (w & 1) * 64;
  int m16 = lane & 15, q = lane >> 4;
  f32x4 acc[4][4] = {};
  int srow = tid >> 1, scol = (tid & 1) * 32;
  const u16* aptr = A + (size_t)(bm + srow) * 1024 + scol;
  const u16* bptr = B + (size_t)(bn + srow) * 1024 + scol;
  uint4 a0 = *(const uint4*)(aptr);
  uint4 a1 = *(const uint4*)(aptr + 8);
  uint4 a2 = *(const uint4*)(aptr + 16);
  uint4 a3 = *(const uint4*)(aptr + 24);
  uint4 b0 = *(const uint4*)(bptr);
  uint4 b1 = *(const uint4*)(bptr + 8);
  uint4 b2 = *(const uint4*)(bptr + 16);
  uint4 b3 = *(const uint4*)(bptr + 24);
  for (int k0 = 0; k0 < 1024; k0 += 64) {
    __syncthreads();
    *(uint4*)&As[srow * GLD2 + scol] = a0;
    *(uint4*)&As[srow * GLD2 + scol + 8] = a1;
    *(uint4*)&As[srow * GLD2 + scol + 16] = a2;
    *(uint4*)&As[srow * GLD2 + scol + 24] = a3;
    *(uint4*)&Bs[srow * GLD2 + scol] = b0;
    *(uint4*)&Bs[srow * GLD2 + scol + 8] = b1;
    *(uint4*)&Bs[srow * GLD2 + scol + 16] = b2;
    *(uint4*)&Bs[srow * GLD2 + scol + 24] = b3;
    uint4 na0, na1, na2, na3, nb0, nb1, nb2, nb3;
    if (k0 < 960) {   // issue next-tile loads early; land during compute
      na0 = *(const uint4*)(aptr + k0 + 64);
      na1 = *(const uint4*)(aptr + k0 + 72);
      na2 = *(const uint4*)(aptr + k0 + 80);
      na3 = *(const uint4*)(aptr + k0 + 88);
      nb0 = *(const uint4*)(bptr + k0 + 64);
      nb1 = *(const uint4*)(bptr + k0 + 72);
      nb2 = *(const uint4*)(bptr + k0 + 80);
      nb3 = *(const uint4*)(bptr + k0 + 88);
    }
    __syncthreads();
#pragma unroll
    for (int kh = 0; kh < 2; ++kh) {
      bf16x8 af[4], bfr[4];
#pragma unroll
      for (int mt = 0; mt < 4; ++mt)
        af[mt] = *(const bf16x8*)&As[(wm + mt * 16 + m16) * GLD2 + kh * 32 + q * 8];
#pragma unroll
      for (int nt = 0; nt < 4; ++nt)
        bfr[nt] = *(const bf16x8*)&Bs[(wn + nt * 16 + m16) * GLD2 + kh * 32 + q * 8];
#pragma unroll
      for (int mt = 0; mt < 4; ++mt)
#pragma unroll
        for (int nt = 0; nt < 4; ++nt)
          acc[mt][nt] = __builtin_amdgcn_mfma_f32_16x16x32_bf16(af[mt], bfr[nt], acc[mt][nt], 0, 0, 0);
    }
    if (k0 < 960) {
      a0 = na0; a1 = na1; a2 = na2; a3 = na3;
      b0 = nb0; b1 = nb1; b2 = nb2; b3 = nb3;
    }
  }
  int hh = (bn + wn) >> 6;
  if (z == 2) {
#pragma unroll
    for (int nt = 0; nt < 4; ++nt) {
      int n = bn + wn + nt * 16 + m16;
#pragma unroll
      for (int mt = 0; mt < 4; ++mt) {
        int t0 = bm + wm + mt * 16 + q * 4;
        ushort4 val;
        val.x = f2bf(acc[mt][nt][0]);
        val.y = f2bf(acc[mt][nt][1]);
        val.z = f2bf(acc[mt][nt][2]);
        val.w = f2bf(acc[mt][nt][3]);
        *(ushort4*)(vt + (size_t)n * 2048 + t0) = val;
      }
    }
  } else {
    u16* dst = z ? kb : qb;
    float se0 = s_qk[hh * 64 +  0 + m16] * 32.0f;   // sqrt(1024)=32
    float se1 = s_qk[hh * 64 + 16 + m16] * 32.0f;
    float se2 = s_qk[hh * 64 + 32 + m16] * 32.0f;
    float se3 = s_qk[hh * 64 + 48 + m16] * 32.0f;
#pragma unroll
    for (int mt = 0; mt < 4; ++mt)
#pragma unroll
      for (int r = 0; r < 4; ++r) {
        float ss = acc[mt][0][r] * acc[mt][0][r] + acc[mt][1][r] * acc[mt][1][r]
                 + acc[mt][2][r] * acc[mt][2][r] + acc[mt][3][r] * acc[mt][3][r];
        ss += __shfl_xor(ss, 1); ss += __shfl_xor(ss, 2);
        ss += __shfl_xor(ss, 4); ss += __shfl_xor(ss, 8);
        float inv = rsqrtf(ss + 1e-12f);
        int t = bm + wm + mt * 16 + q * 4 + r;
        float2 cs = rtab[t * 16 + m16];
        float x0 = acc[mt][0][r] * inv * se0;
        float x1 = acc[mt][1][r] * inv * se1;
        float x2 = acc[mt][2][r] * inv * se2;
        float x3 = acc[mt][3][r] * inv * se3;
        size_t off = (size_t)t * 1024 + hh * 64 + m16;
        dst[off]      = f2bf(x0 * cs.x + x2 * cs.y);
        dst[off + 16] = f2bf(x1);
        dst[off + 32] = f2bf(x2 * cs.x - x0 * cs.y);
        dst[off + 48] = f2bf(x3);
      }
  }
}

// ------------- MFMA flash attention, KEY-SPLIT waves, barrier-free loop ----------
// (r7 form, verified 145.6) + s_setprio around MFMA clusters (T5: pays for
// independent waves, m191). grid (16 h, 32 y); 256 thr = 4 waves; qt = 31-y.
#define PLD 40   // P row stride (u16): 32 keys + 8 pad
#define RPD 20   // combine slice row stride (f32): 16 rows + 4 pad
__global__ __launch_bounds__(256) void attn_flash(const u16* __restrict__ qb,
                                                  const u16* __restrict__ kb,
                                                  const u16* __restrict__ vt,
                                                  u16* __restrict__ yb) {
  __shared__ alignas(16) unsigned char smb[12 * 64 * RPD * 4 + 4 * 64 * 4];
  int h = blockIdx.x;
  int qt = 31 - blockIdx.y;
  int t0 = qt * 64;
  int tid = threadIdx.x;
  int lane = tid & 63, w = tid >> 6;
  int m16 = lane & 15, q = lane >> 4;
  u16* pw = (u16*)smb + w * 64 * PLD;
  bf16x8 qa[4][2];
#pragma unroll
  for (int qn = 0; qn < 4; ++qn) {
    const u16* qr = qb + (size_t)(t0 + qn * 16 + m16) * 1024 + h * 64;
    qa[qn][0] = *(const bf16x8*)(qr + q * 8);
    qa[qn][1] = *(const bf16x8*)(qr + 32 + q * 8);
  }
  int wk = w * 32;
  const u16* kbase = kb + (size_t)(wk + m16) * 1024 + h * 64 + q * 8;
  const u16* vbase = vt + (size_t)(h * 64 + m16) * 2048 + wk + q * 8;
  f32x4 Yacc[4][4] = {};
  float lsum[4] = {0.f, 0.f, 0.f, 0.f};
  int nkb = (qt + 2) >> 1;
  bf16x8 kfr[2][2];
#pragma unroll
  for (int kt = 0; kt < 2; ++kt) {
    kfr[kt][0] = *(const bf16x8*)(kbase + kt * 16384);
    kfr[kt][1] = *(const bf16x8*)(kbase + kt * 16384 + 32);
  }
  for (int kbi = 0; kbi < nkb; ++kbi) {
    int kb0 = kbi * 128;
    bf16x8 vfr[4];
#pragma unroll
    for (int nt = 0; nt < 4; ++nt)
      vfr[nt] = *(const bf16x8*)(vbase + (size_t)nt * 32768 + kb0);
    f32x4 ST[2][4] = {};
    __builtin_amdgcn_s_setprio(1);
#pragma unroll
    for (int kt = 0; kt < 2; ++kt)
#pragma unroll
      for (int qn = 0; qn < 4; ++qn) {
        ST[kt][qn] = __builtin_amdgcn_mfma_f32_16x16x32_bf16(kfr[kt][0], qa[qn][0], ST[kt][qn], 0, 0, 0);
        ST[kt][qn] = __builtin_amdgcn_mfma_f32_16x16x32_bf16(kfr[kt][1], qa[qn][1], ST[kt][qn], 0, 0, 0);
      }
    __builtin_amdgcn_s_setprio(0);
    bf16x8 kn[2][2];
    bool more = (kbi + 1 < nkb);
    if (more) {
      const u16* kp = kbase + (size_t)(kb0 + 128) * 1024;
#pragma unroll
      for (int kt = 0; kt < 2; ++kt) {
        kn[kt][0] = *(const bf16x8*)(kp + kt * 16384);
        kn[kt][1] = *(const bf16x8*)(kp + kt * 16384 + 32);
      }
    }
    bool last = (kbi == nkb - 1);
#pragma unroll
    for (int kt = 0; kt < 2; ++kt) {
      int keyb = kb0 + wk + kt * 16 + q * 4;
#pragma unroll
      for (int qn = 0; qn < 4; ++qn) {
        int qr_ = t0 + qn * 16 + m16;
        float p0 = __builtin_amdgcn_exp2f(ST[kt][qn][0] * 0.17312340490667562f);
        float p1 = __builtin_amdgcn_exp2f(ST[kt][qn][1] * 0.17312340490667562f);
        float p2 = __builtin_amdgcn_exp2f(ST[kt][qn][2] * 0.17312340490667562f);
        float p3 = __builtin_amdgcn_exp2f(ST[kt][qn][3] * 0.17312340490667562f);
        if (last) {
          p0 = (keyb + 0 <= qr_) ? p0 : 0.f;
          p1 = (keyb + 1 <= qr_) ? p1 : 0.f;
          p2 = (keyb + 2 <= qr_) ? p2 : 0.f;
          p3 = (keyb + 3 <= qr_) ? p3 : 0.f;
        }
        lsum[qn] += (p0 + p1) + (p2 + p3);
        uint2 pk2;
        pk2.x = cvtpk(p0, p1);
        pk2.y = cvtpk(p2, p3);
        *(uint2*)&pw[(qn * 16 + m16) * PLD + kt * 16 + q * 4] = pk2;
      }
    }
    bf16x8 pa[4];
#pragma unroll
    for (int qn = 0; qn < 4; ++qn)
      pa[qn] = *(const bf16x8*)&pw[(qn * 16 + m16) * PLD + q * 8];
    __builtin_amdgcn_s_setprio(1);
#pragma unroll
    for (int qn = 0; qn < 4; ++qn)
#pragma unroll
      for (int nt = 0; nt < 4; ++nt)
        Yacc[qn][nt] = __builtin_amdgcn_mfma_f32_16x16x32_bf16(pa[qn], vfr[nt], Yacc[qn][nt], 0, 0, 0);
    __builtin_amdgcn_s_setprio(0);
    if (more) {
      kfr[0][0] = kn[0][0]; kfr[0][1] = kn[0][1];
      kfr[1][0] = kn[1][0]; kfr[1][1] = kn[1][1];
    }
  }
#pragma unroll
  for (int qn = 0; qn < 4; ++qn) {
    lsum[qn] += __shfl_xor(lsum[qn], 16);
    lsum[qn] += __shfl_xor(lsum[qn], 32);
  }
  __syncthreads();
  float* Yr = (float*)smb;
  float* Lb = (float*)(smb + 12 * 64 * RPD * 4);
  if (q == 0) {
#pragma unroll
    for (int qn = 0; qn < 4; ++qn) Lb[w * 64 + qn * 16 + m16] = lsum[qn];
  }
#pragma unroll
  for (int qn = 0; qn < 4; ++qn) {
    if (qn != w) {
      int idx = w * 3 + (qn < w ? qn : qn - 1);
      float* dst = Yr + idx * 64 * RPD;
#pragma unroll
      for (int nt = 0; nt < 4; ++nt)
        *(f32x4*)&dst[(nt * 16 + m16) * RPD + q * 4] = Yacc[qn][nt];
    }
  }
  __syncthreads();
  float Lt[4];
#pragma unroll
  for (int r = 0; r < 4; ++r) {
    int row = w * 16 + q * 4 + r;
    Lt[r] = ((Lb[row] + Lb[64 + row]) + (Lb[128 + row] + Lb[192 + row]));
  }
#pragma unroll
  for (int nt = 0; nt < 4; ++nt) {
    f32x4 y = {0.f, 0.f, 0.f, 0.f};
#pragma unroll
    for (int qn = 0; qn < 4; ++qn)
      if (qn == w) y = Yacc[qn][nt];
#pragma unroll
    for (int wp = 0; wp < 4; ++wp) {
      if (wp != w) {
        int idx = wp * 3 + (w < wp ? w : w - 1);
        f32x4 o = *(const f32x4*)&Yr[idx * 64 * RPD + (nt * 16 + m16) * RPD + q * 4];
        y += o;
      }
    }
#pragma unroll
    for (int r = 0; r < 4; ++r) {
      int t = t0 + w * 16 + q * 4 + r;
      yb[(size_t)t * 1024 + h * 64 + nt * 16 + m16] =
          f2bf(y[r] * __builtin_amdgcn_rcpf(Lt[r]));
    }
  }
}

// ------- o-proj GEMM: out[2048][1024] fp32 = yb bf16 @ Wto^T, BK=64 ------
__global__ __launch_bounds__(256) void gemm_o(const u16* __restrict__ A,
                                              const u16* __restrict__ B,
                                              float* __restrict__ C) {
  __shared__ alignas(16) u16 As[128 * GLD2];
  __shared__ alignas(16) u16 Bs[64 * GLD2];
  int tid = threadIdx.x;
  int bm = blockIdx.y * 128, bn = blockIdx.x * 64;
  int lane = tid & 63, w = tid >> 6;
  int wm = w * 32;
  int m16 = lane & 15, q = lane >> 4;
  f32x4 acc[2][4] = {};
  int srA = tid >> 1, scA = (tid & 1) * 32;
  int srB = tid >> 2, scB = (tid & 3) * 16;
  const u16* aptr = A + (size_t)(bm + srA) * 1024 + scA;
  const u16* bptr = B + (size_t)(bn + srB) * 1024 + scB;
  uint4 a0 = *(const uint4*)(aptr);
  uint4 a1 = *(const uint4*)(aptr + 8);
  uint4 a2 = *(const uint4*)(aptr + 16);
  uint4 a3 = *(const uint4*)(aptr + 24);
  uint4 b0 = *(const uint4*)(bptr);
  uint4 b1 = *(const uint4*)(bptr + 8);
  for (int k0 = 0; k0 < 1024; k0 += 64) {
    __syncthreads();
    *(uint4*)&As[srA * GLD2 + scA] = a0;
    *(uint4*)&As[srA * GLD2 + scA + 8] = a1;
    *(uint4*)&As[srA * GLD2 + scA + 16] = a2;
    *(uint4*)&As[srA * GLD2 + scA + 24] = a3;
    *(uint4*)&Bs[srB * GLD2 + scB] = b0;
    *(uint4*)&Bs[srB * GLD2 + scB + 8] = b1;
    uint4 na0, na1, na2, na3, nb0, nb1;
    if (k0 < 960) {
      na0 = *(const uint4*)(aptr + k0 + 64);
      na1 = *(const uint4*)(aptr + k0 + 72);
      na2 = *(const uint4*)(aptr + k0 + 80);
      na3 = *(const uint4*)(aptr + k0 + 88);
      nb0 = *(const uint4*)(bptr + k0 + 64);
      nb1 = *(const uint4*)(bptr + k0 + 72);
    }
    __syncthreads();
#pragma unroll
    for (int kh = 0; kh < 2; ++kh) {
      bf16x8 af[2], bfr[4];
#pragma unroll
      for (int mt = 0; mt < 2; ++mt)
        af[mt] = *(const bf16x8*)&As[(wm + mt * 16 + m16) * GLD2 + kh * 32 + q * 8];
#pragma unroll
      for (int nt = 0; nt < 4; ++nt)
        bfr[nt] = *(const bf16x8*)&Bs[(nt * 16 + m16) * GLD2 + kh * 32 + q * 8];
#pragma unroll
      for (int mt = 0; mt < 2; ++mt)
#pragma unroll
        for (int nt = 0; nt < 4; ++nt)
          acc[mt][nt] = __builtin_amdgcn_mfma_f32_16x16x32_bf16(af[mt], bfr[nt], acc[mt][nt], 0, 0, 0);
    }
    if (k0 < 960) { a0 = na0; a1 = na1; a2 = na2; a3 = na3; b0 = nb0; b1 = nb1; }
  }
#pragma unroll
  for (int mt = 0; mt < 2; ++mt)
#pragma unroll
    for (int nt = 0; nt < 4; ++nt)
#pragma unroll
      for (int r = 0; r < 4; ++r) {
        int row = bm + wm + mt * 16 + q * 4 + r;
        int col = bn + nt * 16 + m16;
        C[(size_t)row * 1024 + col] = acc[mt][nt][r];
      }
}

extern "C" void kernel_launch(void* const* d_in, const int* in_sizes, int n_in,
                              void* d_out, int out_size, void* d_ws, size_t ws_size,
                              hipStream_t stream) {
  const float* x   = (const float*)d_in[0];
  const float* Wq  = (const float*)d_in[1];
  const float* Wk  = (const float*)d_in[2];
  const float* Wv  = (const float*)d_in[3];
  const float* Wo  = (const float*)d_in[4];
  const float* sqk = (const float*)d_in[5];
  float* out = (float*)d_out;
  char* ws = (char*)d_ws;

  u16*    xb   = (u16*)ws;
  u16*    Wt   = (u16*)(ws + ((size_t)4 << 20));
  float2* rtab = (float2*)(ws + ((size_t)12 << 20));
  u16*    qb16 = (u16*)(ws + ((size_t)16 << 20));
  u16*    kb16 = (u16*)(ws + ((size_t)20 << 20));
  u16*    vt16 = (u16*)(ws + ((size_t)24 << 20));
  u16*    yb   = (u16*)(ws + ((size_t)28 << 20));
  u16*    Wto  = Wt + (size_t)3 * 1024 * 1024;

  prep<<<3072, 256, 0, stream>>>(x, Wq, Wk, Wv, Wo, xb, Wt, rtab);
  gemm_qkv<<<dim3(8, 16, 3), 256, 0, stream>>>(xb, Wt, qb16, kb16, vt16, sqk, rtab);
  attn_flash<<<dim3(16, 32), 256, 0, stream>>>(qb16, kb16, vt16, yb);
  gemm_o<<<dim3(16, 16), 256, 0, stream>>>(yb, Wto, out);
}

// Round 11
// 138.272 us; speedup vs baseline: 1.1364x; 1.0385x over previous
//
#include <hip/hip_runtime.h>

typedef unsigned short u16;
typedef unsigned int u32;
typedef __attribute__((ext_vector_type(8))) short bf16x8;
typedef __attribute__((ext_vector_type(4))) float f32x4;

__device__ __forceinline__ u16 f2bf(float x) {
  unsigned u = __float_as_uint(x);
  u += 0x7fffu + ((u >> 16) & 1u);   // RNE
  return (u16)(u >> 16);
}
__device__ __forceinline__ float bf2f(u16 z) {
  return __uint_as_float((u32)z << 16);
}
__device__ __forceinline__ u32 cvtpk(float lo, float hi) {
  u32 r;
  asm("v_cvt_pk_bf16_f32 %0, %1, %2" : "=v"(r) : "v"(lo), "v"(hi));
  return r;
}

// ---- merged prep: blocks 0..2047 cast x fp32->bf16 (+rope table);
// ----              blocks 2048..3071 transpose+cast the 4 weights ----
__global__ __launch_bounds__(256) void prep(const float* __restrict__ x,
                                            const float* __restrict__ W0,
                                            const float* __restrict__ W1,
                                            const float* __restrict__ W2,
                                            const float* __restrict__ W3,
                                            u16* __restrict__ xb,
                                            u16* __restrict__ Wt,
                                            float2* __restrict__ rtab) {
  __shared__ alignas(16) u16 ls[64 * 72];
  int b = blockIdx.x;
  int tid = threadIdx.x;
  if (b < 2048) {
    int g = b * 256 + tid;
    int i = g * 4;
    float4 f = *(const float4*)(x + i);
    ushort4 o;
    o.x = f2bf(f.x); o.y = f2bf(f.y); o.z = f2bf(f.z); o.w = f2bf(f.w);
    *(ushort4*)(xb + i) = o;
    if (g < 2048 * 16) {
      int t = g >> 4, ii = g & 15;
      float fr = exp2f(-10.0f * (float)ii / 15.0f);
      float th = (float)t * fr;
      rtab[g] = make_float2(cosf(th), sinf(th));
    }
    return;
  }
  int bb = b - 2048;
  int z = bb >> 8;
  int rem = bb & 255;
  const float* W = (z == 0) ? W0 : (z == 1) ? W1 : (z == 2) ? W2 : W3;
  u16* o = Wt + (size_t)z * (1024u * 1024u);
  int kt = (rem >> 4) * 64, nt = (rem & 15) * 64;
  int r = tid >> 2, c0 = (tid & 3) * 16;
  const float* src = W + (size_t)(kt + r) * 1024 + nt + c0;
  u16 tmp[16];
#pragma unroll
  for (int c = 0; c < 16; c += 4) {
    float4 f = *(const float4*)(src + c);
    tmp[c + 0] = f2bf(f.x); tmp[c + 1] = f2bf(f.y);
    tmp[c + 2] = f2bf(f.z); tmp[c + 3] = f2bf(f.w);
  }
#pragma unroll
  for (int c = 0; c < 16; ++c) ls[r * 72 + c0 + c] = tmp[c];
  __syncthreads();
#pragma unroll
  for (int pass = 0; pass < 4; ++pass) {
    int n = pass * 16 + (tid >> 4);
    int kk = (tid & 15) * 4;
    ushort4 val;
    val.x = ls[(kk + 0) * 72 + n];
    val.y = ls[(kk + 1) * 72 + n];
    val.z = ls[(kk + 2) * 72 + n];
    val.w = ls[(kk + 3) * 72 + n];
    *(ushort4*)(o + (size_t)(nt + n) * 1024 + kt + kk) = val;
  }
}

#define GLD2 72  // LDS stride for BK=64 tiles: rows alias at +8 -> 2-way (free)

// ---- fused QKV GEMM 128x128, full K=1024, BK=64 (16 iters, half the barriers) ----
__global__ __launch_bounds__(256) void gemm_qkv(const u16* __restrict__ A,
                                                const u16* __restrict__ Wt,
                                                u16* __restrict__ qb,
                                                u16* __restrict__ kb,
                                                u16* __restrict__ vt,
                                                const float* __restrict__ s_qk,
                                                const float2* __restrict__ rtab) {
  __shared__ alignas(16) u16 As[128 * GLD2];
  __shared__ alignas(16) u16 Bs[128 * GLD2];
  int z = blockIdx.z;
  const u16* B = Wt + (size_t)z * (1024u * 1024u);
  int tid = threadIdx.x;
  int bm = blockIdx.y * 128, bn = blockIdx.x * 128;
  int lane = tid & 63, w = tid >> 6;
  int wm = (w >> 1) * 64, wn = (w & 1) * 64;
  int m16 = lane & 15, q = lane >> 4;
  f32x4 acc[4][4] = {};
  int srow = tid >> 1, scol = (tid & 1) * 32;
  const u16* aptr = A + (size_t)(bm + srow) * 1024 + scol;
  const u16* bptr = B + (size_t)(bn + srow) * 1024 + scol;
  uint4 a0 = *(const uint4*)(aptr);
  uint4 a1 = *(const uint4*)(aptr + 8);
  uint4 a2 = *(const uint4*)(aptr + 16);
  uint4 a3 = *(const uint4*)(aptr + 24);
  uint4 b0 = *(const uint4*)(bptr);
  uint4 b1 = *(const uint4*)(bptr + 8);
  uint4 b2 = *(const uint4*)(bptr + 16);
  uint4 b3 = *(const uint4*)(bptr + 24);
  for (int k0 = 0; k0 < 1024; k0 += 64) {
    __syncthreads();
    *(uint4*)&As[srow * GLD2 + scol] = a0;
    *(uint4*)&As[srow * GLD2 + scol + 8] = a1;
    *(uint4*)&As[srow * GLD2 + scol + 16] = a2;
    *(uint4*)&As[srow * GLD2 + scol + 24] = a3;
    *(uint4*)&Bs[srow * GLD2 + scol] = b0;
    *(uint4*)&Bs[srow * GLD2 + scol + 8] = b1;
    *(uint4*)&Bs[srow * GLD2 + scol + 16] = b2;
    *(uint4*)&Bs[srow * GLD2 + scol + 24] = b3;
    uint4 na0, na1, na2, na3, nb0, nb1, nb2, nb3;
    if (k0 < 960) {   // issue next-tile loads early; land during compute
      na0 = *(const uint4*)(aptr + k0 + 64);
      na1 = *(const uint4*)(aptr + k0 + 72);
      na2 = *(const uint4*)(aptr + k0 + 80);
      na3 = *(const uint4*)(aptr + k0 + 88);
      nb0 = *(const uint4*)(bptr + k0 + 64);
      nb1 = *(const uint4*)(bptr + k0 + 72);
      nb2 = *(const uint4*)(bptr + k0 + 80);
      nb3 = *(const uint4*)(bptr + k0 + 88);
    }
    __syncthreads();
#pragma unroll
    for (int kh = 0; kh < 2; ++kh) {
      bf16x8 af[4], bfr[4];
#pragma unroll
      for (int mt = 0; mt < 4; ++mt)
        af[mt] = *(const bf16x8*)&As[(wm + mt * 16 + m16) * GLD2 + kh * 32 + q * 8];
#pragma unroll
      for (int nt = 0; nt < 4; ++nt)
        bfr[nt] = *(const bf16x8*)&Bs[(wn + nt * 16 + m16) * GLD2 + kh * 32 + q * 8];
#pragma unroll
      for (int mt = 0; mt < 4; ++mt)
#pragma unroll
        for (int nt = 0; nt < 4; ++nt)
          acc[mt][nt] = __builtin_amdgcn_mfma_f32_16x16x32_bf16(af[mt], bfr[nt], acc[mt][nt], 0, 0, 0);
    }
    if (k0 < 960) {
      a0 = na0; a1 = na1; a2 = na2; a3 = na3;
      b0 = nb0; b1 = nb1; b2 = nb2; b3 = nb3;
    }
  }
  int hh = (bn + wn) >> 6;
  if (z == 2) {
#pragma unroll
    for (int nt = 0; nt < 4; ++nt) {
      int n = bn + wn + nt * 16 + m16;
#pragma unroll
      for (int mt = 0; mt < 4; ++mt) {
        int t0 = bm + wm + mt * 16 + q * 4;
        ushort4 val;
        val.x = f2bf(acc[mt][nt][0]);
        val.y = f2bf(acc[mt][nt][1]);
        val.z = f2bf(acc[mt][nt][2]);
        val.w = f2bf(acc[mt][nt][3]);
        *(ushort4*)(vt + (size_t)n * 2048 + t0) = val;
      }
    }
  } else {
    u16* dst = z ? kb : qb;
    float se0 = s_qk[hh * 64 +  0 + m16] * 32.0f;   // sqrt(1024)=32
    float se1 = s_qk[hh * 64 + 16 + m16] * 32.0f;
    float se2 = s_qk[hh * 64 + 32 + m16] * 32.0f;
    float se3 = s_qk[hh * 64 + 48 + m16] * 32.0f;
#pragma unroll
    for (int mt = 0; mt < 4; ++mt)
#pragma unroll
      for (int r = 0; r < 4; ++r) {
        float ss = acc[mt][0][r] * acc[mt][0][r] + acc[mt][1][r] * acc[mt][1][r]
                 + acc[mt][2][r] * acc[mt][2][r] + acc[mt][3][r] * acc[mt][3][r];
        ss += __shfl_xor(ss, 1); ss += __shfl_xor(ss, 2);
        ss += __shfl_xor(ss, 4); ss += __shfl_xor(ss, 8);
        float inv = rsqrtf(ss + 1e-12f);
        int t = bm + wm + mt * 16 + q * 4 + r;
        float2 cs = rtab[t * 16 + m16];
        float x0 = acc[mt][0][r] * inv * se0;
        float x1 = acc[mt][1][r] * inv * se1;
        float x2 = acc[mt][2][r] * inv * se2;
        float x3 = acc[mt][3][r] * inv * se3;
        size_t off = (size_t)t * 1024 + hh * 64 + m16;
        dst[off]      = f2bf(x0 * cs.x + x2 * cs.y);
        dst[off + 16] = f2bf(x1);
        dst[off + 32] = f2bf(x2 * cs.x - x0 * cs.y);
        dst[off + 48] = f2bf(x3);
      }
  }
}

// ------------- MFMA flash attention, KEY-SPLIT waves, barrier-free loop ----------
// grid (16 h, 32 y); 256 thr = 4 waves. BALANCED FOLD: qt = y<16 ? 31-y : y-16,
// so co-resident pair (bid, bid+256) = (31-y, y) -> uniform ~17.5 key-tile units
// per CU (old qt=31-y pairing gave 25-y: 1.43x tail). Heavy half dispatches first.
// Wave w owns keys [kb0+w*32,+32) of each 128-key block; K AND V are register-
// prefetched one full iteration ahead (L2 latency cover). No barriers in loop.
#define PLD 40   // P row stride (u16): 32 keys + 8 pad
#define RPD 20   // combine slice row stride (f32): 16 rows + 4 pad
__global__ __launch_bounds__(256) void attn_flash(const u16* __restrict__ qb,
                                                  const u16* __restrict__ kb,
                                                  const u16* __restrict__ vt,
                                                  u16* __restrict__ yb) {
  __shared__ alignas(16) unsigned char smb[12 * 64 * RPD * 4 + 4 * 64 * 4];
  int h = blockIdx.x;
  int y = blockIdx.y;
  int qt = (y < 16) ? (31 - y) : (y - 16);   // balanced fold pairing
  int t0 = qt * 64;
  int tid = threadIdx.x;
  int lane = tid & 63, w = tid >> 6;
  int m16 = lane & 15, q = lane >> 4;
  u16* pw = (u16*)smb + w * 64 * PLD;
  bf16x8 qa[4][2];
#pragma unroll
  for (int qn = 0; qn < 4; ++qn) {
    const u16* qr = qb + (size_t)(t0 + qn * 16 + m16) * 1024 + h * 64;
    qa[qn][0] = *(const bf16x8*)(qr + q * 8);
    qa[qn][1] = *(const bf16x8*)(qr + 32 + q * 8);
  }
  int wk = w * 32;
  const u16* kbase = kb + (size_t)(wk + m16) * 1024 + h * 64 + q * 8;
  const u16* vbase = vt + (size_t)(h * 64 + m16) * 2048 + wk + q * 8;
  f32x4 Yacc[4][4] = {};
  float lsum[4] = {0.f, 0.f, 0.f, 0.f};
  int nkb = (qt + 2) >> 1;
  bf16x8 kfr[2][2], vfr[4];
#pragma unroll
  for (int kt = 0; kt < 2; ++kt) {
    kfr[kt][0] = *(const bf16x8*)(kbase + kt * 16384);
    kfr[kt][1] = *(const bf16x8*)(kbase + kt * 16384 + 32);
  }
#pragma unroll
  for (int nt = 0; nt < 4; ++nt)
    vfr[nt] = *(const bf16x8*)(vbase + (size_t)nt * 32768);
  for (int kbi = 0; kbi < nkb; ++kbi) {
    int kb0 = kbi * 128;
    f32x4 ST[2][4] = {};
    __builtin_amdgcn_s_setprio(1);
#pragma unroll
    for (int kt = 0; kt < 2; ++kt)
#pragma unroll
      for (int qn = 0; qn < 4; ++qn) {
        ST[kt][qn] = __builtin_amdgcn_mfma_f32_16x16x32_bf16(kfr[kt][0], qa[qn][0], ST[kt][qn], 0, 0, 0);
        ST[kt][qn] = __builtin_amdgcn_mfma_f32_16x16x32_bf16(kfr[kt][1], qa[qn][1], ST[kt][qn], 0, 0, 0);
      }
    __builtin_amdgcn_s_setprio(0);
    bf16x8 kn[2][2], vn[4];
    bool more = (kbi + 1 < nkb);
    if (more) {   // prefetch next block's K and V a full iteration ahead
      const u16* kp = kbase + (size_t)(kb0 + 128) * 1024;
#pragma unroll
      for (int kt = 0; kt < 2; ++kt) {
        kn[kt][0] = *(const bf16x8*)(kp + kt * 16384);
        kn[kt][1] = *(const bf16x8*)(kp + kt * 16384 + 32);
      }
#pragma unroll
      for (int nt = 0; nt < 4; ++nt)
        vn[nt] = *(const bf16x8*)(vbase + (size_t)nt * 32768 + kb0 + 128);
    }
    bool last = (kbi == nkb - 1);
#pragma unroll
    for (int kt = 0; kt < 2; ++kt) {
      int keyb = kb0 + wk + kt * 16 + q * 4;
#pragma unroll
      for (int qn = 0; qn < 4; ++qn) {
        int qr_ = t0 + qn * 16 + m16;
        float p0 = __builtin_amdgcn_exp2f(ST[kt][qn][0] * 0.17312340490667562f);
        float p1 = __builtin_amdgcn_exp2f(ST[kt][qn][1] * 0.17312340490667562f);
        float p2 = __builtin_amdgcn_exp2f(ST[kt][qn][2] * 0.17312340490667562f);
        float p3 = __builtin_amdgcn_exp2f(ST[kt][qn][3] * 0.17312340490667562f);
        if (last) {
          p0 = (keyb + 0 <= qr_) ? p0 : 0.f;
          p1 = (keyb + 1 <= qr_) ? p1 : 0.f;
          p2 = (keyb + 2 <= qr_) ? p2 : 0.f;
          p3 = (keyb + 3 <= qr_) ? p3 : 0.f;
        }
        lsum[qn] += (p0 + p1) + (p2 + p3);
        uint2 pk2;
        pk2.x = cvtpk(p0, p1);
        pk2.y = cvtpk(p2, p3);
        *(uint2*)&pw[(qn * 16 + m16) * PLD + kt * 16 + q * 4] = pk2;
      }
    }
    bf16x8 pa[4];
#pragma unroll
    for (int qn = 0; qn < 4; ++qn)
      pa[qn] = *(const bf16x8*)&pw[(qn * 16 + m16) * PLD + q * 8];
    __builtin_amdgcn_s_setprio(1);
#pragma unroll
    for (int qn = 0; qn < 4; ++qn)
#pragma unroll
      for (int nt = 0; nt < 4; ++nt)
        Yacc[qn][nt] = __builtin_amdgcn_mfma_f32_16x16x32_bf16(pa[qn], vfr[nt], Yacc[qn][nt], 0, 0, 0);
    __builtin_amdgcn_s_setprio(0);
    if (more) {
      kfr[0][0] = kn[0][0]; kfr[0][1] = kn[0][1];
      kfr[1][0] = kn[1][0]; kfr[1][1] = kn[1][1];
      vfr[0] = vn[0]; vfr[1] = vn[1]; vfr[2] = vn[2]; vfr[3] = vn[3];
    }
  }
#pragma unroll
  for (int qn = 0; qn < 4; ++qn) {
    lsum[qn] += __shfl_xor(lsum[qn], 16);
    lsum[qn] += __shfl_xor(lsum[qn], 32);
  }
  __syncthreads();
  float* Yr = (float*)smb;
  float* Lb = (float*)(smb + 12 * 64 * RPD * 4);
  if (q == 0) {
#pragma unroll
    for (int qn = 0; qn < 4; ++qn) Lb[w * 64 + qn * 16 + m16] = lsum[qn];
  }
#pragma unroll
  for (int qn = 0; qn < 4; ++qn) {
    if (qn != w) {
      int idx = w * 3 + (qn < w ? qn : qn - 1);
      float* dst = Yr + idx * 64 * RPD;
#pragma unroll
      for (int nt = 0; nt < 4; ++nt)
        *(f32x4*)&dst[(nt * 16 + m16) * RPD + q * 4] = Yacc[qn][nt];
    }
  }
  __syncthreads();
  float Lt[4];
#pragma unroll
  for (int r = 0; r < 4; ++r) {
    int row = w * 16 + q * 4 + r;
    Lt[r] = ((Lb[row] + Lb[64 + row]) + (Lb[128 + row] + Lb[192 + row]));
  }
#pragma unroll
  for (int nt = 0; nt < 4; ++nt) {
    f32x4 y2 = {0.f, 0.f, 0.f, 0.f};
#pragma unroll
    for (int qn = 0; qn < 4; ++qn)
      if (qn == w) y2 = Yacc[qn][nt];
#pragma unroll
    for (int wp = 0; wp < 4; ++wp) {
      if (wp != w) {
        int idx = wp * 3 + (w < wp ? w : w - 1);
        f32x4 o = *(const f32x4*)&Yr[idx * 64 * RPD + (nt * 16 + m16) * RPD + q * 4];
        y2 += o;
      }
    }
#pragma unroll
    for (int r = 0; r < 4; ++r) {
      int t = t0 + w * 16 + q * 4 + r;
      yb[(size_t)t * 1024 + h * 64 + nt * 16 + m16] =
          f2bf(y2[r] * __builtin_amdgcn_rcpf(Lt[r]));
    }
  }
}

// ------- o-proj GEMM: out[2048][1024] fp32 = yb bf16 @ Wto^T, BK=64 ------
__global__ __launch_bounds__(256) void gemm_o(const u16* __restrict__ A,
                                              const u16* __restrict__ B,
                                              float* __restrict__ C) {
  __shared__ alignas(16) u16 As[128 * GLD2];
  __shared__ alignas(16) u16 Bs[64 * GLD2];
  int tid = threadIdx.x;
  int bm = blockIdx.y * 128, bn = blockIdx.x * 64;
  int lane = tid & 63, w = tid >> 6;
  int wm = w * 32;
  int m16 = lane & 15, q = lane >> 4;
  f32x4 acc[2][4] = {};
  int srA = tid >> 1, scA = (tid & 1) * 32;
  int srB = tid >> 2, scB = (tid & 3) * 16;
  const u16* aptr = A + (size_t)(bm + srA) * 1024 + scA;
  const u16* bptr = B + (size_t)(bn + srB) * 1024 + scB;
  uint4 a0 = *(const uint4*)(aptr);
  uint4 a1 = *(const uint4*)(aptr + 8);
  uint4 a2 = *(const uint4*)(aptr + 16);
  uint4 a3 = *(const uint4*)(aptr + 24);
  uint4 b0 = *(const uint4*)(bptr);
  uint4 b1 = *(const uint4*)(bptr + 8);
  for (int k0 = 0; k0 < 1024; k0 += 64) {
    __syncthreads();
    *(uint4*)&As[srA * GLD2 + scA] = a0;
    *(uint4*)&As[srA * GLD2 + scA + 8] = a1;
    *(uint4*)&As[srA * GLD2 + scA + 16] = a2;
    *(uint4*)&As[srA * GLD2 + scA + 24] = a3;
    *(uint4*)&Bs[srB * GLD2 + scB] = b0;
    *(uint4*)&Bs[srB * GLD2 + scB + 8] = b1;
    uint4 na0, na1, na2, na3, nb0, nb1;
    if (k0 < 960) {
      na0 = *(const uint4*)(aptr + k0 + 64);
      na1 = *(const uint4*)(aptr + k0 + 72);
      na2 = *(const uint4*)(aptr + k0 + 80);
      na3 = *(const uint4*)(aptr + k0 + 88);
      nb0 = *(const uint4*)(bptr + k0 + 64);
      nb1 = *(const uint4*)(bptr + k0 + 72);
    }
    __syncthreads();
#pragma unroll
    for (int kh = 0; kh < 2; ++kh) {
      bf16x8 af[2], bfr[4];
#pragma unroll
      for (int mt = 0; mt < 2; ++mt)
        af[mt] = *(const bf16x8*)&As[(wm + mt * 16 + m16) * GLD2 + kh * 32 + q * 8];
#pragma unroll
      for (int nt = 0; nt < 4; ++nt)
        bfr[nt] = *(const bf16x8*)&Bs[(nt * 16 + m16) * GLD2 + kh * 32 + q * 8];
#pragma unroll
      for (int mt = 0; mt < 2; ++mt)
#pragma unroll
        for (int nt = 0; nt < 4; ++nt)
          acc[mt][nt] = __builtin_amdgcn_mfma_f32_16x16x32_bf16(af[mt], bfr[nt], acc[mt][nt], 0, 0, 0);
    }
    if (k0 < 960) { a0 = na0; a1 = na1; a2 = na2; a3 = na3; b0 = nb0; b1 = nb1; }
  }
#pragma unroll
  for (int mt = 0; mt < 2; ++mt)
#pragma unroll
    for (int nt = 0; nt < 4; ++nt)
#pragma unroll
      for (int r = 0; r < 4; ++r) {
        int row = bm + wm + mt * 16 + q * 4 + r;
        int col = bn + nt * 16 + m16;
        C[(size_t)row * 1024 + col] = acc[mt][nt][r];
      }
}

extern "C" void kernel_launch(void* const* d_in, const int* in_sizes, int n_in,
                              void* d_out, int out_size, void* d_ws, size_t ws_size,
                              hipStream_t stream) {
  const float* x   = (const float*)d_in[0];
  const float* Wq  = (const float*)d_in[1];
  const float* Wk  = (const float*)d_in[2];
  const float* Wv  = (const float*)d_in[3];
  const float* Wo  = (const float*)d_in[4];
  const float* sqk = (const float*)d_in[5];
  float* out = (float*)d_out;
  char* ws = (char*)d_ws;

  u16*    xb   = (u16*)ws;
  u16*    Wt   = (u16*)(ws + ((size_t)4 << 20));
  float2* rtab = (float2*)(ws + ((size_t)12 << 20));
  u16*    qb16 = (u16*)(ws + ((size_t)16 << 20));
  u16*    kb16 = (u16*)(ws + ((size_t)20 << 20));
  u16*    vt16 = (u16*)(ws + ((size_t)24 << 20));
  u16*    yb   = (u16*)(ws + ((size_t)28 << 20));
  u16*    Wto  = Wt + (size_t)3 * 1024 * 1024;

  prep<<<3072, 256, 0, stream>>>(x, Wq, Wk, Wv, Wo, xb, Wt, rtab);
  gemm_qkv<<<dim3(8, 16, 3), 256, 0, stream>>>(xb, Wt, qb16, kb16, vt16, sqk, rtab);
  attn_flash<<<dim3(16, 32), 256, 0, stream>>>(qb16, kb16, vt16, yb);
  gemm_o<<<dim3(16, 16), 256, 0, stream>>>(yb, Wto, out);
}

// Round 12
// 136.253 us; speedup vs baseline: 1.1532x; 1.0148x over previous
//
#include <hip/hip_runtime.h>

typedef unsigned short u16;
typedef unsigned int u32;
typedef __attribute__((ext_vector_type(8))) short bf16x8;
typedef __attribute__((ext_vector_type(4))) float f32x4;

__device__ __forceinline__ u16 f2bf(float x) {
  unsigned u = __float_as_uint(x);
  u += 0x7fffu + ((u >> 16) & 1u);   // RNE
  return (u16)(u >> 16);
}
__device__ __forceinline__ float bf2f(u16 z) {
  return __uint_as_float((u32)z << 16);
}
__device__ __forceinline__ u32 cvtpk(float lo, float hi) {
  u32 r;
  asm("v_cvt_pk_bf16_f32 %0, %1, %2" : "=v"(r) : "v"(lo), "v"(hi));
  return r;
}

// ---- merged prep: blocks 0..2047 cast x fp32->bf16 (+rope table);
// ----              blocks 2048..3071 transpose+cast the 4 weights ----
__global__ __launch_bounds__(256) void prep(const float* __restrict__ x,
                                            const float* __restrict__ W0,
                                            const float* __restrict__ W1,
                                            const float* __restrict__ W2,
                                            const float* __restrict__ W3,
                                            u16* __restrict__ xb,
                                            u16* __restrict__ Wt,
                                            float2* __restrict__ rtab) {
  __shared__ alignas(16) u16 ls[64 * 72];
  int b = blockIdx.x;
  int tid = threadIdx.x;
  if (b < 2048) {
    int g = b * 256 + tid;
    int i = g * 4;
    float4 f = *(const float4*)(x + i);
    ushort4 o;
    o.x = f2bf(f.x); o.y = f2bf(f.y); o.z = f2bf(f.z); o.w = f2bf(f.w);
    *(ushort4*)(xb + i) = o;
    if (g < 2048 * 16) {
      int t = g >> 4, ii = g & 15;
      float fr = exp2f(-10.0f * (float)ii / 15.0f);
      float th = (float)t * fr;
      rtab[g] = make_float2(cosf(th), sinf(th));
    }
    return;
  }
  int bb = b - 2048;
  int z = bb >> 8;
  int rem = bb & 255;
  const float* W = (z == 0) ? W0 : (z == 1) ? W1 : (z == 2) ? W2 : W3;
  u16* o = Wt + (size_t)z * (1024u * 1024u);
  int kt = (rem >> 4) * 64, nt = (rem & 15) * 64;
  int r = tid >> 2, c0 = (tid & 3) * 16;
  const float* src = W + (size_t)(kt + r) * 1024 + nt + c0;
  u16 tmp[16];
#pragma unroll
  for (int c = 0; c < 16; c += 4) {
    float4 f = *(const float4*)(src + c);
    tmp[c + 0] = f2bf(f.x); tmp[c + 1] = f2bf(f.y);
    tmp[c + 2] = f2bf(f.z); tmp[c + 3] = f2bf(f.w);
  }
#pragma unroll
  for (int c = 0; c < 16; ++c) ls[r * 72 + c0 + c] = tmp[c];
  __syncthreads();
#pragma unroll
  for (int pass = 0; pass < 4; ++pass) {
    int n = pass * 16 + (tid >> 4);
    int kk = (tid & 15) * 4;
    ushort4 val;
    val.x = ls[(kk + 0) * 72 + n];
    val.y = ls[(kk + 1) * 72 + n];
    val.z = ls[(kk + 2) * 72 + n];
    val.w = ls[(kk + 3) * 72 + n];
    *(ushort4*)(o + (size_t)(nt + n) * 1024 + kt + kk) = val;
  }
}

#define GLD2 72  // LDS stride for BK=64 tiles: rows alias at +8 -> 2-way (free)

// ---- fused QKV GEMM 128x128, full K=1024, BK=64, 512 thr / 8 waves ----
// Waves 4m x 2n (32x64 out each): same tiles/traffic as r11, 2x waves/SIMD
// (1.5 -> 3). Staging 4 loads/thread; reg prefetch kept; epilogue per-wave
// still owns one full head (wn in {0,64}).
__global__ __launch_bounds__(512) void gemm_qkv(const u16* __restrict__ A,
                                                const u16* __restrict__ Wt,
                                                u16* __restrict__ qb,
                                                u16* __restrict__ kb,
                                                u16* __restrict__ vt,
                                                const float* __restrict__ s_qk,
                                                const float2* __restrict__ rtab) {
  __shared__ alignas(16) u16 As[128 * GLD2];
  __shared__ alignas(16) u16 Bs[128 * GLD2];
  int z = blockIdx.z;
  const u16* B = Wt + (size_t)z * (1024u * 1024u);
  int tid = threadIdx.x;
  int bm = blockIdx.y * 128, bn = blockIdx.x * 128;
  int lane = tid & 63, w = tid >> 6;          // w in 0..7
  int wm = (w >> 1) * 32, wn = (w & 1) * 64;
  int m16 = lane & 15, q = lane >> 4;
  f32x4 acc[2][4] = {};
  int srow = tid >> 2, scol = (tid & 3) * 16;  // 4 thr/row, 16 u16 each
  const u16* aptr = A + (size_t)(bm + srow) * 1024 + scol;
  const u16* bptr = B + (size_t)(bn + srow) * 1024 + scol;
  uint4 a0 = *(const uint4*)(aptr);
  uint4 a1 = *(const uint4*)(aptr + 8);
  uint4 b0 = *(const uint4*)(bptr);
  uint4 b1 = *(const uint4*)(bptr + 8);
  for (int k0 = 0; k0 < 1024; k0 += 64) {
    __syncthreads();
    *(uint4*)&As[srow * GLD2 + scol] = a0;
    *(uint4*)&As[srow * GLD2 + scol + 8] = a1;
    *(uint4*)&Bs[srow * GLD2 + scol] = b0;
    *(uint4*)&Bs[srow * GLD2 + scol + 8] = b1;
    uint4 na0, na1, nb0, nb1;
    if (k0 < 960) {   // issue next-tile loads early; land during compute
      na0 = *(const uint4*)(aptr + k0 + 64);
      na1 = *(const uint4*)(aptr + k0 + 72);
      nb0 = *(const uint4*)(bptr + k0 + 64);
      nb1 = *(const uint4*)(bptr + k0 + 72);
    }
    __syncthreads();
#pragma unroll
    for (int kh = 0; kh < 2; ++kh) {
      bf16x8 af[2], bfr[4];
#pragma unroll
      for (int mt = 0; mt < 2; ++mt)
        af[mt] = *(const bf16x8*)&As[(wm + mt * 16 + m16) * GLD2 + kh * 32 + q * 8];
#pragma unroll
      for (int nt = 0; nt < 4; ++nt)
        bfr[nt] = *(const bf16x8*)&Bs[(wn + nt * 16 + m16) * GLD2 + kh * 32 + q * 8];
#pragma unroll
      for (int mt = 0; mt < 2; ++mt)
#pragma unroll
        for (int nt = 0; nt < 4; ++nt)
          acc[mt][nt] = __builtin_amdgcn_mfma_f32_16x16x32_bf16(af[mt], bfr[nt], acc[mt][nt], 0, 0, 0);
    }
    if (k0 < 960) { a0 = na0; a1 = na1; b0 = nb0; b1 = nb1; }
  }
  int hh = (bn + wn) >> 6;
  if (z == 2) {
#pragma unroll
    for (int nt = 0; nt < 4; ++nt) {
      int n = bn + wn + nt * 16 + m16;
#pragma unroll
      for (int mt = 0; mt < 2; ++mt) {
        int t0 = bm + wm + mt * 16 + q * 4;
        ushort4 val;
        val.x = f2bf(acc[mt][nt][0]);
        val.y = f2bf(acc[mt][nt][1]);
        val.z = f2bf(acc[mt][nt][2]);
        val.w = f2bf(acc[mt][nt][3]);
        *(ushort4*)(vt + (size_t)n * 2048 + t0) = val;
      }
    }
  } else {
    u16* dst = z ? kb : qb;
    float se0 = s_qk[hh * 64 +  0 + m16] * 32.0f;   // sqrt(1024)=32
    float se1 = s_qk[hh * 64 + 16 + m16] * 32.0f;
    float se2 = s_qk[hh * 64 + 32 + m16] * 32.0f;
    float se3 = s_qk[hh * 64 + 48 + m16] * 32.0f;
#pragma unroll
    for (int mt = 0; mt < 2; ++mt)
#pragma unroll
      for (int r = 0; r < 4; ++r) {
        float ss = acc[mt][0][r] * acc[mt][0][r] + acc[mt][1][r] * acc[mt][1][r]
                 + acc[mt][2][r] * acc[mt][2][r] + acc[mt][3][r] * acc[mt][3][r];
        ss += __shfl_xor(ss, 1); ss += __shfl_xor(ss, 2);
        ss += __shfl_xor(ss, 4); ss += __shfl_xor(ss, 8);
        float inv = rsqrtf(ss + 1e-12f);
        int t = bm + wm + mt * 16 + q * 4 + r;
        float2 cs = rtab[t * 16 + m16];
        float x0 = acc[mt][0][r] * inv * se0;
        float x1 = acc[mt][1][r] * inv * se1;
        float x2 = acc[mt][2][r] * inv * se2;
        float x3 = acc[mt][3][r] * inv * se3;
        size_t off = (size_t)t * 1024 + hh * 64 + m16;
        dst[off]      = f2bf(x0 * cs.x + x2 * cs.y);
        dst[off + 16] = f2bf(x1);
        dst[off + 32] = f2bf(x2 * cs.x - x0 * cs.y);
        dst[off + 48] = f2bf(x3);
      }
  }
}

// ------------- MFMA flash attention, KEY-SPLIT waves, barrier-free loop ----------
// (r11 form, verified 138.3) grid (16 h, 32 y); 256 thr = 4 waves.
// Balanced fold: qt = y<16 ? 31-y : y-16 -> uniform ~17.5 key-tile units/CU.
#define PLD 40   // P row stride (u16): 32 keys + 8 pad
#define RPD 20   // combine slice row stride (f32): 16 rows + 4 pad
__global__ __launch_bounds__(256) void attn_flash(const u16* __restrict__ qb,
                                                  const u16* __restrict__ kb,
                                                  const u16* __restrict__ vt,
                                                  u16* __restrict__ yb) {
  __shared__ alignas(16) unsigned char smb[12 * 64 * RPD * 4 + 4 * 64 * 4];
  int h = blockIdx.x;
  int y = blockIdx.y;
  int qt = (y < 16) ? (31 - y) : (y - 16);   // balanced fold pairing
  int t0 = qt * 64;
  int tid = threadIdx.x;
  int lane = tid & 63, w = tid >> 6;
  int m16 = lane & 15, q = lane >> 4;
  u16* pw = (u16*)smb + w * 64 * PLD;
  bf16x8 qa[4][2];
#pragma unroll
  for (int qn = 0; qn < 4; ++qn) {
    const u16* qr = qb + (size_t)(t0 + qn * 16 + m16) * 1024 + h * 64;
    qa[qn][0] = *(const bf16x8*)(qr + q * 8);
    qa[qn][1] = *(const bf16x8*)(qr + 32 + q * 8);
  }
  int wk = w * 32;
  const u16* kbase = kb + (size_t)(wk + m16) * 1024 + h * 64 + q * 8;
  const u16* vbase = vt + (size_t)(h * 64 + m16) * 2048 + wk + q * 8;
  f32x4 Yacc[4][4] = {};
  float lsum[4] = {0.f, 0.f, 0.f, 0.f};
  int nkb = (qt + 2) >> 1;
  bf16x8 kfr[2][2], vfr[4];
#pragma unroll
  for (int kt = 0; kt < 2; ++kt) {
    kfr[kt][0] = *(const bf16x8*)(kbase + kt * 16384);
    kfr[kt][1] = *(const bf16x8*)(kbase + kt * 16384 + 32);
  }
#pragma unroll
  for (int nt = 0; nt < 4; ++nt)
    vfr[nt] = *(const bf16x8*)(vbase + (size_t)nt * 32768);
  for (int kbi = 0; kbi < nkb; ++kbi) {
    int kb0 = kbi * 128;
    f32x4 ST[2][4] = {};
    __builtin_amdgcn_s_setprio(1);
#pragma unroll
    for (int kt = 0; kt < 2; ++kt)
#pragma unroll
      for (int qn = 0; qn < 4; ++qn) {
        ST[kt][qn] = __builtin_amdgcn_mfma_f32_16x16x32_bf16(kfr[kt][0], qa[qn][0], ST[kt][qn], 0, 0, 0);
        ST[kt][qn] = __builtin_amdgcn_mfma_f32_16x16x32_bf16(kfr[kt][1], qa[qn][1], ST[kt][qn], 0, 0, 0);
      }
    __builtin_amdgcn_s_setprio(0);
    bf16x8 kn[2][2], vn[4];
    bool more = (kbi + 1 < nkb);
    if (more) {   // prefetch next block's K and V a full iteration ahead
      const u16* kp = kbase + (size_t)(kb0 + 128) * 1024;
#pragma unroll
      for (int kt = 0; kt < 2; ++kt) {
        kn[kt][0] = *(const bf16x8*)(kp + kt * 16384);
        kn[kt][1] = *(const bf16x8*)(kp + kt * 16384 + 32);
      }
#pragma unroll
      for (int nt = 0; nt < 4; ++nt)
        vn[nt] = *(const bf16x8*)(vbase + (size_t)nt * 32768 + kb0 + 128);
    }
    bool last = (kbi == nkb - 1);
#pragma unroll
    for (int kt = 0; kt < 2; ++kt) {
      int keyb = kb0 + wk + kt * 16 + q * 4;
#pragma unroll
      for (int qn = 0; qn < 4; ++qn) {
        int qr_ = t0 + qn * 16 + m16;
        float p0 = __builtin_amdgcn_exp2f(ST[kt][qn][0] * 0.17312340490667562f);
        float p1 = __builtin_amdgcn_exp2f(ST[kt][qn][1] * 0.17312340490667562f);
        float p2 = __builtin_amdgcn_exp2f(ST[kt][qn][2] * 0.17312340490667562f);
        float p3 = __builtin_amdgcn_exp2f(ST[kt][qn][3] * 0.17312340490667562f);
        if (last) {
          p0 = (keyb + 0 <= qr_) ? p0 : 0.f;
          p1 = (keyb + 1 <= qr_) ? p1 : 0.f;
          p2 = (keyb + 2 <= qr_) ? p2 : 0.f;
          p3 = (keyb + 3 <= qr_) ? p3 : 0.f;
        }
        lsum[qn] += (p0 + p1) + (p2 + p3);
        uint2 pk2;
        pk2.x = cvtpk(p0, p1);
        pk2.y = cvtpk(p2, p3);
        *(uint2*)&pw[(qn * 16 + m16) * PLD + kt * 16 + q * 4] = pk2;
      }
    }
    bf16x8 pa[4];
#pragma unroll
    for (int qn = 0; qn < 4; ++qn)
      pa[qn] = *(const bf16x8*)&pw[(qn * 16 + m16) * PLD + q * 8];
    __builtin_amdgcn_s_setprio(1);
#pragma unroll
    for (int qn = 0; qn < 4; ++qn)
#pragma unroll
      for (int nt = 0; nt < 4; ++nt)
        Yacc[qn][nt] = __builtin_amdgcn_mfma_f32_16x16x32_bf16(pa[qn], vfr[nt], Yacc[qn][nt], 0, 0, 0);
    __builtin_amdgcn_s_setprio(0);
    if (more) {
      kfr[0][0] = kn[0][0]; kfr[0][1] = kn[0][1];
      kfr[1][0] = kn[1][0]; kfr[1][1] = kn[1][1];
      vfr[0] = vn[0]; vfr[1] = vn[1]; vfr[2] = vn[2]; vfr[3] = vn[3];
    }
  }
#pragma unroll
  for (int qn = 0; qn < 4; ++qn) {
    lsum[qn] += __shfl_xor(lsum[qn], 16);
    lsum[qn] += __shfl_xor(lsum[qn], 32);
  }
  __syncthreads();
  float* Yr = (float*)smb;
  float* Lb = (float*)(smb + 12 * 64 * RPD * 4);
  if (q == 0) {
#pragma unroll
    for (int qn = 0; qn < 4; ++qn) Lb[w * 64 + qn * 16 + m16] = lsum[qn];
  }
#pragma unroll
  for (int qn = 0; qn < 4; ++qn) {
    if (qn != w) {
      int idx = w * 3 + (qn < w ? qn : qn - 1);
      float* dst = Yr + idx * 64 * RPD;
#pragma unroll
      for (int nt = 0; nt < 4; ++nt)
        *(f32x4*)&dst[(nt * 16 + m16) * RPD + q * 4] = Yacc[qn][nt];
    }
  }
  __syncthreads();
  float Lt[4];
#pragma unroll
  for (int r = 0; r < 4; ++r) {
    int row = w * 16 + q * 4 + r;
    Lt[r] = ((Lb[row] + Lb[64 + row]) + (Lb[128 + row] + Lb[192 + row]));
  }
#pragma unroll
  for (int nt = 0; nt < 4; ++nt) {
    f32x4 y2 = {0.f, 0.f, 0.f, 0.f};
#pragma unroll
    for (int qn = 0; qn < 4; ++qn)
      if (qn == w) y2 = Yacc[qn][nt];
#pragma unroll
    for (int wp = 0; wp < 4; ++wp) {
      if (wp != w) {
        int idx = wp * 3 + (w < wp ? w : w - 1);
        f32x4 o = *(const f32x4*)&Yr[idx * 64 * RPD + (nt * 16 + m16) * RPD + q * 4];
        y2 += o;
      }
    }
#pragma unroll
    for (int r = 0; r < 4; ++r) {
      int t = t0 + w * 16 + q * 4 + r;
      yb[(size_t)t * 1024 + h * 64 + nt * 16 + m16] =
          f2bf(y2[r] * __builtin_amdgcn_rcpf(Lt[r]));
    }
  }
}

// ------- o-proj GEMM: out[2048][1024] fp32 = yb bf16 @ Wto^T, BK=64 ------
// 512 thr / 8 waves (4m x 2n, 32x32 out each): waves/SIMD 1 -> 2.
__global__ __launch_bounds__(512) void gemm_o(const u16* __restrict__ A,
                                              const u16* __restrict__ B,
                                              float* __restrict__ C) {
  __shared__ alignas(16) u16 As[128 * GLD2];
  __shared__ alignas(16) u16 Bs[64 * GLD2];
  int tid = threadIdx.x;
  int bm = blockIdx.y * 128, bn = blockIdx.x * 64;
  int lane = tid & 63, w = tid >> 6;          // 0..7
  int wm = (w >> 1) * 32, wn = (w & 1) * 32;
  int m16 = lane & 15, q = lane >> 4;
  f32x4 acc[2][2] = {};
  int srA = tid >> 2, scA = (tid & 3) * 16;   // A: 128 rows, 4 thr/row
  int srB = tid >> 3, scB = (tid & 7) * 8;    // B: 64 rows, 8 thr/row
  const u16* aptr = A + (size_t)(bm + srA) * 1024 + scA;
  const u16* bptr = B + (size_t)(bn + srB) * 1024 + scB;
  uint4 a0 = *(const uint4*)(aptr);
  uint4 a1 = *(const uint4*)(aptr + 8);
  uint4 b0 = *(const uint4*)(bptr);
  for (int k0 = 0; k0 < 1024; k0 += 64) {
    __syncthreads();
    *(uint4*)&As[srA * GLD2 + scA] = a0;
    *(uint4*)&As[srA * GLD2 + scA + 8] = a1;
    *(uint4*)&Bs[srB * GLD2 + scB] = b0;
    uint4 na0, na1, nb0;
    if (k0 < 960) {
      na0 = *(const uint4*)(aptr + k0 + 64);
      na1 = *(const uint4*)(aptr + k0 + 72);
      nb0 = *(const uint4*)(bptr + k0 + 64);
    }
    __syncthreads();
#pragma unroll
    for (int kh = 0; kh < 2; ++kh) {
      bf16x8 af[2], bfr[2];
#pragma unroll
      for (int mt = 0; mt < 2; ++mt)
        af[mt] = *(const bf16x8*)&As[(wm + mt * 16 + m16) * GLD2 + kh * 32 + q * 8];
#pragma unroll
      for (int nt = 0; nt < 2; ++nt)
        bfr[nt] = *(const bf16x8*)&Bs[(wn + nt * 16 + m16) * GLD2 + kh * 32 + q * 8];
#pragma unroll
      for (int mt = 0; mt < 2; ++mt)
#pragma unroll
        for (int nt = 0; nt < 2; ++nt)
          acc[mt][nt] = __builtin_amdgcn_mfma_f32_16x16x32_bf16(af[mt], bfr[nt], acc[mt][nt], 0, 0, 0);
    }
    if (k0 < 960) { a0 = na0; a1 = na1; b0 = nb0; }
  }
#pragma unroll
  for (int mt = 0; mt < 2; ++mt)
#pragma unroll
    for (int nt = 0; nt < 2; ++nt)
#pragma unroll
      for (int r = 0; r < 4; ++r) {
        int row = bm + wm + mt * 16 + q * 4 + r;
        int col = bn + wn + nt * 16 + m16;
        C[(size_t)row * 1024 + col] = acc[mt][nt][r];
      }
}

extern "C" void kernel_launch(void* const* d_in, const int* in_sizes, int n_in,
                              void* d_out, int out_size, void* d_ws, size_t ws_size,
                              hipStream_t stream) {
  const float* x   = (const float*)d_in[0];
  const float* Wq  = (const float*)d_in[1];
  const float* Wk  = (const float*)d_in[2];
  const float* Wv  = (const float*)d_in[3];
  const float* Wo  = (const float*)d_in[4];
  const float* sqk = (const float*)d_in[5];
  float* out = (float*)d_out;
  char* ws = (char*)d_ws;

  u16*    xb   = (u16*)ws;
  u16*    Wt   = (u16*)(ws + ((size_t)4 << 20));
  float2* rtab = (float2*)(ws + ((size_t)12 << 20));
  u16*    qb16 = (u16*)(ws + ((size_t)16 << 20));
  u16*    kb16 = (u16*)(ws + ((size_t)20 << 20));
  u16*    vt16 = (u16*)(ws + ((size_t)24 << 20));
  u16*    yb   = (u16*)(ws + ((size_t)28 << 20));
  u16*    Wto  = Wt + (size_t)3 * 1024 * 1024;

  prep<<<3072, 256, 0, stream>>>(x, Wq, Wk, Wv, Wo, xb, Wt, rtab);
  gemm_qkv<<<dim3(8, 16, 3), 512, 0, stream>>>(xb, Wt, qb16, kb16, vt16, sqk, rtab);
  attn_flash<<<dim3(16, 32), 256, 0, stream>>>(qb16, kb16, vt16, yb);
  gemm_o<<<dim3(16, 16), 512, 0, stream>>>(yb, Wto, out);
}